// Round 6
// baseline (276.561 us; speedup 1.0000x reference)
//
#include <hip/hip_runtime.h>

#define N_NODES 65536
#define N_EDGES 1048576
#define NB 256            // coarse buckets = dst >> 8
#define CAP 4608          // per-bucket capacity: mean 4096 + 8 sigma (binomial)
#define EPB_A 2048        // edges per block in bin_pass
#define BLK_A (N_EDGES / EPB_A)   // 512
#define EPT_A (EPB_A / 256)       // 8 edges per thread

typedef __attribute__((ext_vector_type(8))) short short8v;   // 8 bf16 (4 VGPRs)
typedef __attribute__((ext_vector_type(4))) float float4v;   // MFMA C/D

// fp32 -> bf16 round-to-nearest-even
__device__ __forceinline__ unsigned short f2bf(float f) {
  unsigned u = __float_as_uint(f);
  unsigned r = u + 0x7FFFu + ((u >> 16) & 1u);
  return (unsigned short)(r >> 16);
}
__device__ __forceinline__ float bflo(unsigned u) { return __uint_as_float(u << 16); }
__device__ __forceinline__ float bfhi(unsigned u) { return __uint_as_float(u & 0xFFFF0000u); }

// ---------------------------------------------------------------------------
// JAX threefry2x32, partitionable path: bits[i] = x0^x1 of
// threefry2x32(key=(0,42), counter=(0,i)); keep = MSB==0.  [verified R1]
// ---------------------------------------------------------------------------
__device__ __forceinline__ bool keep_mask(unsigned idx) {
  const unsigned k0 = 0u, k1 = 42u;
  const unsigned k2 = 0x1BD11BDAu ^ k0 ^ k1;
  unsigned x0 = 0u;
  unsigned x1 = idx;
  x0 += k0; x1 += k1;
#define TF_ROUND(r) { x0 += x1; x1 = (x1 << (r)) | (x1 >> (32 - (r))); x1 ^= x0; }
  TF_ROUND(13) TF_ROUND(15) TF_ROUND(26) TF_ROUND(6)
  x0 += k1; x1 += k2 + 1u;
  TF_ROUND(17) TF_ROUND(29) TF_ROUND(16) TF_ROUND(24)
  x0 += k2; x1 += k0 + 2u;
  TF_ROUND(13) TF_ROUND(15) TF_ROUND(26) TF_ROUND(6)
  x0 += k0; x1 += k1 + 3u;
  TF_ROUND(17) TF_ROUND(29) TF_ROUND(16) TF_ROUND(24)
  x0 += k1; x1 += k2 + 4u;
  TF_ROUND(13) TF_ROUND(15) TF_ROUND(26) TF_ROUND(6)
  x0 += k2; x1 += k0 + 5u;
#undef TF_ROUND
  return ((x0 ^ x1) & 0x80000000u) == 0u;
}

// ===========================================================================
// prep_w1: Wt[ch][k] = bf16(W1[k][ch]), K zero-padded 300 -> 320.
// Block 0 also zeroes the 256 bucket cursors (stream order covers bin_pass).
// ===========================================================================
__global__ __launch_bounds__(256) void prep_w1(const float* __restrict__ W1,
                                               unsigned short* __restrict__ Wt,
                                               unsigned* __restrict__ gcur) {
  if (blockIdx.x == 0) gcur[threadIdx.x] = 0u;
  int i = blockIdx.x * 256 + threadIdx.x;
  if (i >= 64 * 320) return;
  int ch = i / 320, k = i % 320;
  float v = (k < 300) ? W1[k * 64 + ch] : 0.0f;
  Wt[i] = f2bf(v);
}

// ===========================================================================
// Sort stage 1: multisplit into fixed-capacity bucket regions.
// pack: x = src | (dst << 16), y = weight fp32 bits
// ===========================================================================
__global__ __launch_bounds__(256) void bin_pass(const int* __restrict__ ei,
                                                const float* __restrict__ ew,
                                                unsigned* __restrict__ gcur,
                                                uint2* __restrict__ binned) {
  __shared__ unsigned cnt[NB], lofs[NB], lcur[NB], gbase[NB];
  __shared__ uint2 stage[EPB_A];
  const int t = threadIdx.x;
  const int e0 = blockIdx.x * EPB_A;
  cnt[t] = 0u;
  lcur[t] = 0u;
  __syncthreads();
  unsigned pk[EPT_A], pw[EPT_A];
#pragma unroll
  for (int j = 0; j < EPT_A; ++j) {
    int e = e0 + t + j * 256;
    unsigned s = (unsigned)ei[e];
    unsigned d = (unsigned)ei[N_EDGES + e];
    pk[j] = s | (d << 16);
    pw[j] = __float_as_uint(ew[e]);
    atomicAdd(&cnt[d >> 8], 1u);
  }
  __syncthreads();
  lofs[t] = cnt[t];
  __syncthreads();
  for (int d = 1; d < NB; d <<= 1) {
    unsigned u = (t >= d) ? lofs[t - d] : 0u;
    __syncthreads();
    lofs[t] += u;
    __syncthreads();
  }
  unsigned incl = lofs[t];
  lofs[t] = incl - cnt[t];
  gbase[t] = (unsigned)t * CAP + atomicAdd(&gcur[t], cnt[t]);
  __syncthreads();
#pragma unroll
  for (int j = 0; j < EPT_A; ++j) {
    unsigned b = pk[j] >> 24;
    unsigned slot = lofs[b] + atomicAdd(&lcur[b], 1u);
    stage[slot] = make_uint2(pk[j], pw[j]);
  }
  __syncthreads();
  for (int s = t; s < EPB_A; s += 256) {
    uint2 u = stage[s];
    unsigned b = u.x >> 24;
    binned[gbase[b] + ((unsigned)s - lofs[b])] = u;
  }
}

// ===========================================================================
// Sort stage 2: per-bucket counting sort by dst low-8; emits CSR offs/ends.
// sorted entry compressed to 4B: src | bf16(w) << 16
// ===========================================================================
__global__ __launch_bounds__(256) void bucket_sort(const unsigned* __restrict__ gcur,
                                                   const uint2* __restrict__ binned,
                                                   unsigned* __restrict__ sortedc,
                                                   unsigned* __restrict__ offs_g,
                                                   unsigned* __restrict__ ends_g) {
  __shared__ unsigned cnt[NB], cur[NB];
  const int t = threadIdx.x;
  const int b = blockIdx.x;
  const unsigned lo = (unsigned)b * CAP;
  const unsigned hi = lo + gcur[b];
  cnt[t] = 0u;
  __syncthreads();
  for (unsigned i = lo + t; i < hi; i += 256) {
    unsigned lo8 = (binned[i].x >> 16) & 255u;
    atomicAdd(&cnt[lo8], 1u);
  }
  __syncthreads();
  cur[t] = cnt[t];
  __syncthreads();
  for (int d = 1; d < NB; d <<= 1) {
    unsigned u = (t >= d) ? cur[t - d] : 0u;
    __syncthreads();
    cur[t] += u;
    __syncthreads();
  }
  unsigned excl = cur[t] - cnt[t];
  unsigned node_start = lo + excl;
  offs_g[b * NB + t] = node_start;
  ends_g[b * NB + t] = node_start + cnt[t];
  __syncthreads();
  cur[t] = excl;
  __syncthreads();
  for (unsigned i = lo + t; i < hi; i += 256) {
    uint2 u = binned[i];
    unsigned lo8 = (u.x >> 16) & 255u;
    unsigned p = lo + atomicAdd(&cur[lo8], 1u);
    sortedc[p] = (u.x & 0xFFFFu) | ((unsigned)f2bf(__uint_as_float(u.y)) << 16);
  }
}

// ===========================================================================
// gemm1_mfma: h1 = x @ W1 via bf16 MFMA 16x16x32; h1 stored bf16 (8 MB).
// ===========================================================================
__global__ __launch_bounds__(256) void gemm1_mfma(const float* __restrict__ x,
                                                  const unsigned short* __restrict__ Wt,
                                                  unsigned short* __restrict__ h1b) {
  __shared__ unsigned short As[64][72];
  __shared__ unsigned short Bs[64][72];
  const int t = threadIdx.x;
  const int node0 = blockIdx.x * 64;
  const int wave = t >> 6, lane = t & 63;
  const int quad = lane >> 4, l16 = lane & 15;
  float4v acc[4] = {{0.f,0.f,0.f,0.f},{0.f,0.f,0.f,0.f},{0.f,0.f,0.f,0.f},{0.f,0.f,0.f,0.f}};

  for (int kt = 0; kt < 5; ++kt) {
    const int k0 = kt * 64;
    for (int f = t; f < 1024; f += 256) {
      int node = f >> 4;
      int k = (f & 15) * 4;
      uint2 packed;
      if (k0 + k < 300) {
        float4 v = *(const float4*)(x + (size_t)(node0 + node) * 300 + k0 + k);
        packed.x = (unsigned)f2bf(v.x) | ((unsigned)f2bf(v.y) << 16);
        packed.y = (unsigned)f2bf(v.z) | ((unsigned)f2bf(v.w) << 16);
      } else {
        packed.x = 0u; packed.y = 0u;
      }
      *(uint2*)&As[node][k] = packed;
    }
    for (int f = t; f < 512; f += 256) {
      int ch = f >> 3;
      int kq = f & 7;
      uint4 v = *(const uint4*)(Wt + (size_t)ch * 320 + k0 + kq * 8);
      *(uint4*)&Bs[ch][kq * 8] = v;
    }
    __syncthreads();
    short8v a0 = *(const short8v*)&As[wave * 16 + l16][quad * 8];
    short8v a1 = *(const short8v*)&As[wave * 16 + l16][32 + quad * 8];
#pragma unroll
    for (int nt = 0; nt < 4; ++nt) {
      short8v b0 = *(const short8v*)&Bs[nt * 16 + l16][quad * 8];
      short8v b1 = *(const short8v*)&Bs[nt * 16 + l16][32 + quad * 8];
      acc[nt] = __builtin_amdgcn_mfma_f32_16x16x32_bf16(a0, b0, acc[nt], 0, 0, 0);
      acc[nt] = __builtin_amdgcn_mfma_f32_16x16x32_bf16(a1, b1, acc[nt], 0, 0, 0);
    }
    __syncthreads();
  }
#pragma unroll
  for (int nt = 0; nt < 4; ++nt) {
#pragma unroll
    for (int r = 0; r < 4; ++r) {
      h1b[(size_t)(node0 + wave * 16 + quad * 4 + r) * 64 + nt * 16 + l16] = f2bf(acc[nt][r]);
    }
  }
}

// ===========================================================================
// Fused layer-1 aggregate + relu/dropout + gemm2.  ONE WAVE PER NODE:
// 64 lanes = 16 ch-lanes (cg) x 4 edge-slots (q) -> 4x gathers in flight;
// butterfly shfl_xor(16,32) reduce; quad 0 holds the h2 row.
// g stored bf16 padded to 32 ch (one 64B line per node).
// ===========================================================================
__global__ __launch_bounds__(256) void agg1_gemm2(const unsigned* __restrict__ offs_g,
                                                  const unsigned* __restrict__ ends_g,
                                                  const unsigned* __restrict__ sortedc,
                                                  const unsigned short* __restrict__ h1b,
                                                  const float* __restrict__ b1,
                                                  const float* __restrict__ W2,
                                                  unsigned* __restrict__ g32u) {
  __shared__ float w2t[20][68];   // transposed W2
  __shared__ float h2[4][68];     // per-wave h2 row
  __shared__ float gtmp[4][20];
  const int t = threadIdx.x;
  for (int i = t; i < 64 * 20; i += 256) {
    w2t[i % 20][i / 20] = W2[i];
  }
  const int wave = t >> 6, lane = t & 63;
  const int q = lane >> 4, cg = lane & 15;
  const int node = blockIdx.x * 4 + wave;
  const unsigned s = offs_g[node], e_end = ends_g[node];
  float4 acc = (q == 0) ? *(const float4*)(b1 + cg * 4) : make_float4(0.f, 0.f, 0.f, 0.f);
  for (unsigned i = s + q; i < e_end; i += 4) {
    unsigned ec = sortedc[i];
    uint2 v = *(const uint2*)(h1b + ((size_t)(ec & 0xFFFFu)) * 64 + cg * 4);
    float w = bfhi(ec);
    acc.x = fmaf(w, bflo(v.x), acc.x); acc.y = fmaf(w, bfhi(v.x), acc.y);
    acc.z = fmaf(w, bflo(v.y), acc.z); acc.w = fmaf(w, bfhi(v.y), acc.w);
  }
  // reduce over edge-slots (lanes differing in bits 4,5)
  acc.x += __shfl_xor(acc.x, 16); acc.y += __shfl_xor(acc.y, 16);
  acc.z += __shfl_xor(acc.z, 16); acc.w += __shfl_xor(acc.w, 16);
  acc.x += __shfl_xor(acc.x, 32); acc.y += __shfl_xor(acc.y, 32);
  acc.z += __shfl_xor(acc.z, 32); acc.w += __shfl_xor(acc.w, 32);
  if (q == 0) {
    const unsigned gi = (unsigned)node * 64u + (unsigned)cg * 4u;
    float r[4] = {acc.x, acc.y, acc.z, acc.w};
#pragma unroll
    for (int j = 0; j < 4; ++j) {
      float v = fmaxf(r[j], 0.0f);
      h2[wave][cg * 4 + j] = keep_mask(gi + j) ? v * 2.0f : 0.0f;
    }
  }
  __syncthreads();
  // gemm2: lanes 0..19 of each wave compute their node's 20 outputs
  if (lane < 20) {
    float d = 0.0f;
#pragma unroll
    for (int k = 0; k < 64; k += 4) {
      float4 hv = *(const float4*)(&h2[wave][k]);
      float4 wv = *(const float4*)(&w2t[lane][k]);
      d = fmaf(hv.x, wv.x, d); d = fmaf(hv.y, wv.y, d);
      d = fmaf(hv.z, wv.z, d); d = fmaf(hv.w, wv.w, d);
    }
    gtmp[wave][lane] = d;
  }
  __syncthreads();
  if (lane < 16) {
    int c0 = lane * 2;
    unsigned packed = 0u;
    if (c0 < 20) {
      packed = (unsigned)f2bf(gtmp[wave][c0]) |
               ((c0 + 1 < 20) ? ((unsigned)f2bf(gtmp[wave][c0 + 1]) << 16) : 0u);
    }
    g32u[(size_t)node * 16 + lane] = packed;
  }
}

// ===========================================================================
// aggregate2: out[n][c] = b2[c] + sum_e w * g[src][c]
// ONE WAVE PER NODE: 16 ch-lanes (uint = 2ch) x 4 edge-slots, butterfly reduce.
// ===========================================================================
__global__ __launch_bounds__(256) void aggregate2(const unsigned* __restrict__ offs_g,
                                                  const unsigned* __restrict__ ends_g,
                                                  const unsigned* __restrict__ sortedc,
                                                  const unsigned* __restrict__ g32u,
                                                  const float* __restrict__ b2,
                                                  float* __restrict__ out) {
  const int t = threadIdx.x;
  const int wave = t >> 6, lane = t & 63;
  const int q = lane >> 4, cg = lane & 15;
  const int node = blockIdx.x * 4 + wave;
  const unsigned s = offs_g[node], e_end = ends_g[node];
  float ax = 0.0f, ay = 0.0f;
  for (unsigned i = s + q; i < e_end; i += 4) {
    unsigned ec = sortedc[i];
    unsigned v = g32u[(size_t)(ec & 0xFFFFu) * 16 + cg];
    float w = bfhi(ec);
    ax = fmaf(w, bflo(v), ax);
    ay = fmaf(w, bfhi(v), ay);
  }
  ax += __shfl_xor(ax, 16); ay += __shfl_xor(ay, 16);
  ax += __shfl_xor(ax, 32); ay += __shfl_xor(ay, 32);
  if (q == 0 && cg < 10) {
    float2 o = make_float2(ax + b2[cg * 2], ay + b2[cg * 2 + 1]);
    *(float2*)(out + (size_t)node * 20 + cg * 2) = o;
  }
}

extern "C" void kernel_launch(void* const* d_in, const int* in_sizes, int n_in,
                              void* d_out, int out_size, void* d_ws, size_t ws_size,
                              hipStream_t stream) {
  const float* x  = (const float*)d_in[0];
  const int*   ei = (const int*)d_in[1];
  const float* ew = (const float*)d_in[2];
  const float* W1 = (const float*)d_in[3];
  const float* b1 = (const float*)d_in[4];
  const float* W2 = (const float*)d_in[5];
  const float* b2 = (const float*)d_in[6];
  float* out = (float*)d_out;

  // workspace layout (~27 MB; ws confirmed >= 42 MB)
  unsigned short* h1b     = (unsigned short*)d_ws;                  // N*64 bf16, 8MB
  unsigned*       g32u    = (unsigned*)(h1b + (size_t)N_NODES * 64);// N*16 uint, 4MB
  uint2*          binned  = (uint2*)(g32u + (size_t)N_NODES * 16);  // NB*CAP uint2, 9.4MB
  unsigned*       sortedc = (unsigned*)(binned + (size_t)NB * CAP); // NB*CAP uint, 4.7MB
  unsigned*       offs_g  = sortedc + (size_t)NB * CAP;             // N
  unsigned*       ends_g  = offs_g + N_NODES;                       // N
  unsigned short* Wt      = (unsigned short*)(ends_g + N_NODES);    // 64*320 bf16
  unsigned*       gcur    = (unsigned*)(Wt + 64 * 320);             // NB

  prep_w1<<<(64 * 320 + 255) / 256, 256, 0, stream>>>(W1, Wt, gcur);
  bin_pass<<<BLK_A, 256, 0, stream>>>(ei, ew, gcur, binned);
  bucket_sort<<<NB, 256, 0, stream>>>(gcur, binned, sortedc, offs_g, ends_g);
  gemm1_mfma<<<N_NODES / 64, 256, 0, stream>>>(x, Wt, h1b);
  agg1_gemm2<<<N_NODES / 4, 256, 0, stream>>>(offs_g, ends_g, sortedc, h1b, b1, W2, g32u);
  aggregate2<<<N_NODES / 4, 256, 0, stream>>>(offs_g, ends_g, sortedc, g32u, b2, out);
}

// Round 7
// 226.542 us; speedup vs baseline: 1.2208x; 1.2208x over previous
//
#include <hip/hip_runtime.h>

#define N_NODES 65536
#define N_EDGES 1048576
#define NB 256            // coarse buckets = dst >> 8
#define CAP 4608          // per-bucket capacity: mean 4096 + 8 sigma (binomial)
#define EPB_A 2048        // edges per block in bin_pass
#define BLK_A (N_EDGES / EPB_A)   // 512
#define EPT_A (EPB_A / 256)       // 8 edges per thread

typedef __attribute__((ext_vector_type(8))) short short8v;   // 8 bf16 (4 VGPRs)
typedef __attribute__((ext_vector_type(4))) float float4v;   // MFMA C/D

// fp32 -> bf16 round-to-nearest-even
__device__ __forceinline__ unsigned short f2bf(float f) {
  unsigned u = __float_as_uint(f);
  unsigned r = u + 0x7FFFu + ((u >> 16) & 1u);
  return (unsigned short)(r >> 16);
}
__device__ __forceinline__ float bflo(unsigned u) { return __uint_as_float(u << 16); }
__device__ __forceinline__ float bfhi(unsigned u) { return __uint_as_float(u & 0xFFFF0000u); }

// ---------------------------------------------------------------------------
// JAX threefry2x32, partitionable path: bits[i] = x0^x1 of
// threefry2x32(key=(0,42), counter=(0,i)); keep = MSB==0.  [verified R1]
// ---------------------------------------------------------------------------
__device__ __forceinline__ bool keep_mask(unsigned idx) {
  const unsigned k0 = 0u, k1 = 42u;
  const unsigned k2 = 0x1BD11BDAu ^ k0 ^ k1;
  unsigned x0 = 0u;
  unsigned x1 = idx;
  x0 += k0; x1 += k1;
#define TF_ROUND(r) { x0 += x1; x1 = (x1 << (r)) | (x1 >> (32 - (r))); x1 ^= x0; }
  TF_ROUND(13) TF_ROUND(15) TF_ROUND(26) TF_ROUND(6)
  x0 += k1; x1 += k2 + 1u;
  TF_ROUND(17) TF_ROUND(29) TF_ROUND(16) TF_ROUND(24)
  x0 += k2; x1 += k0 + 2u;
  TF_ROUND(13) TF_ROUND(15) TF_ROUND(26) TF_ROUND(6)
  x0 += k0; x1 += k1 + 3u;
  TF_ROUND(17) TF_ROUND(29) TF_ROUND(16) TF_ROUND(24)
  x0 += k1; x1 += k2 + 4u;
  TF_ROUND(13) TF_ROUND(15) TF_ROUND(26) TF_ROUND(6)
  x0 += k2; x1 += k0 + 5u;
#undef TF_ROUND
  return ((x0 ^ x1) & 0x80000000u) == 0u;
}

// ===========================================================================
// prep_w1: Wt[ch][k] = bf16(W1[k][ch]), K zero-padded 300 -> 320.
// Block 0 also zeroes the 256 bucket cursors (stream order covers bin_pass).
// ===========================================================================
__global__ __launch_bounds__(256) void prep_w1(const float* __restrict__ W1,
                                               unsigned short* __restrict__ Wt,
                                               unsigned* __restrict__ gcur) {
  if (blockIdx.x == 0) gcur[threadIdx.x] = 0u;
  int i = blockIdx.x * 256 + threadIdx.x;
  if (i >= 64 * 320) return;
  int ch = i / 320, k = i % 320;
  float v = (k < 300) ? W1[k * 64 + ch] : 0.0f;
  Wt[i] = f2bf(v);
}

// ===========================================================================
// Sort stage 1: multisplit into fixed-capacity bucket regions.
// pack: x = src | (dst << 16), y = weight fp32 bits
// ===========================================================================
__global__ __launch_bounds__(256) void bin_pass(const int* __restrict__ ei,
                                                const float* __restrict__ ew,
                                                unsigned* __restrict__ gcur,
                                                uint2* __restrict__ binned) {
  __shared__ unsigned cnt[NB], lofs[NB], lcur[NB], gbase[NB];
  __shared__ uint2 stage[EPB_A];
  const int t = threadIdx.x;
  const int e0 = blockIdx.x * EPB_A;
  cnt[t] = 0u;
  lcur[t] = 0u;
  __syncthreads();
  unsigned pk[EPT_A], pw[EPT_A];
#pragma unroll
  for (int j = 0; j < EPT_A; ++j) {
    int e = e0 + t + j * 256;
    unsigned s = (unsigned)ei[e];
    unsigned d = (unsigned)ei[N_EDGES + e];
    pk[j] = s | (d << 16);
    pw[j] = __float_as_uint(ew[e]);
    atomicAdd(&cnt[d >> 8], 1u);
  }
  __syncthreads();
  lofs[t] = cnt[t];
  __syncthreads();
  for (int d = 1; d < NB; d <<= 1) {
    unsigned u = (t >= d) ? lofs[t - d] : 0u;
    __syncthreads();
    lofs[t] += u;
    __syncthreads();
  }
  unsigned incl = lofs[t];
  lofs[t] = incl - cnt[t];
  gbase[t] = (unsigned)t * CAP + atomicAdd(&gcur[t], cnt[t]);
  __syncthreads();
#pragma unroll
  for (int j = 0; j < EPT_A; ++j) {
    unsigned b = pk[j] >> 24;
    unsigned slot = lofs[b] + atomicAdd(&lcur[b], 1u);
    stage[slot] = make_uint2(pk[j], pw[j]);
  }
  __syncthreads();
  for (int s = t; s < EPB_A; s += 256) {
    uint2 u = stage[s];
    unsigned b = u.x >> 24;
    binned[gbase[b] + ((unsigned)s - lofs[b])] = u;
  }
}

// ===========================================================================
// Sort stage 2: per-bucket counting sort by dst low-8; emits CSR offs/ends.
// sorted entry compressed to 4B: src | bf16(w) << 16
// ===========================================================================
__global__ __launch_bounds__(256) void bucket_sort(const unsigned* __restrict__ gcur,
                                                   const uint2* __restrict__ binned,
                                                   unsigned* __restrict__ sortedc,
                                                   unsigned* __restrict__ offs_g,
                                                   unsigned* __restrict__ ends_g) {
  __shared__ unsigned cnt[NB], cur[NB];
  const int t = threadIdx.x;
  const int b = blockIdx.x;
  const unsigned lo = (unsigned)b * CAP;
  const unsigned hi = lo + gcur[b];
  cnt[t] = 0u;
  __syncthreads();
  for (unsigned i = lo + t; i < hi; i += 256) {
    unsigned lo8 = (binned[i].x >> 16) & 255u;
    atomicAdd(&cnt[lo8], 1u);
  }
  __syncthreads();
  cur[t] = cnt[t];
  __syncthreads();
  for (int d = 1; d < NB; d <<= 1) {
    unsigned u = (t >= d) ? cur[t - d] : 0u;
    __syncthreads();
    cur[t] += u;
    __syncthreads();
  }
  unsigned excl = cur[t] - cnt[t];
  unsigned node_start = lo + excl;
  offs_g[b * NB + t] = node_start;
  ends_g[b * NB + t] = node_start + cnt[t];
  __syncthreads();
  cur[t] = excl;
  __syncthreads();
  for (unsigned i = lo + t; i < hi; i += 256) {
    uint2 u = binned[i];
    unsigned lo8 = (u.x >> 16) & 255u;
    unsigned p = lo + atomicAdd(&cur[lo8], 1u);
    sortedc[p] = (u.x & 0xFFFFu) | ((unsigned)f2bf(__uint_as_float(u.y)) << 16);
  }
}

// ===========================================================================
// gemm1_mfma: h1 = x @ W1 via bf16 MFMA 16x16x32; h1 stored bf16 (8 MB).
// ===========================================================================
__global__ __launch_bounds__(256) void gemm1_mfma(const float* __restrict__ x,
                                                  const unsigned short* __restrict__ Wt,
                                                  unsigned short* __restrict__ h1b) {
  __shared__ unsigned short As[64][72];
  __shared__ unsigned short Bs[64][72];
  const int t = threadIdx.x;
  const int node0 = blockIdx.x * 64;
  const int wave = t >> 6, lane = t & 63;
  const int quad = lane >> 4, l16 = lane & 15;
  float4v acc[4] = {{0.f,0.f,0.f,0.f},{0.f,0.f,0.f,0.f},{0.f,0.f,0.f,0.f},{0.f,0.f,0.f,0.f}};

  for (int kt = 0; kt < 5; ++kt) {
    const int k0 = kt * 64;
    for (int f = t; f < 1024; f += 256) {
      int node = f >> 4;
      int k = (f & 15) * 4;
      uint2 packed;
      if (k0 + k < 300) {
        float4 v = *(const float4*)(x + (size_t)(node0 + node) * 300 + k0 + k);
        packed.x = (unsigned)f2bf(v.x) | ((unsigned)f2bf(v.y) << 16);
        packed.y = (unsigned)f2bf(v.z) | ((unsigned)f2bf(v.w) << 16);
      } else {
        packed.x = 0u; packed.y = 0u;
      }
      *(uint2*)&As[node][k] = packed;
    }
    for (int f = t; f < 512; f += 256) {
      int ch = f >> 3;
      int kq = f & 7;
      uint4 v = *(const uint4*)(Wt + (size_t)ch * 320 + k0 + kq * 8);
      *(uint4*)&Bs[ch][kq * 8] = v;
    }
    __syncthreads();
    short8v a0 = *(const short8v*)&As[wave * 16 + l16][quad * 8];
    short8v a1 = *(const short8v*)&As[wave * 16 + l16][32 + quad * 8];
#pragma unroll
    for (int nt = 0; nt < 4; ++nt) {
      short8v b0 = *(const short8v*)&Bs[nt * 16 + l16][quad * 8];
      short8v b1 = *(const short8v*)&Bs[nt * 16 + l16][32 + quad * 8];
      acc[nt] = __builtin_amdgcn_mfma_f32_16x16x32_bf16(a0, b0, acc[nt], 0, 0, 0);
      acc[nt] = __builtin_amdgcn_mfma_f32_16x16x32_bf16(a1, b1, acc[nt], 0, 0, 0);
    }
    __syncthreads();
  }
#pragma unroll
  for (int nt = 0; nt < 4; ++nt) {
#pragma unroll
    for (int r = 0; r < 4; ++r) {
      h1b[(size_t)(node0 + wave * 16 + quad * 4 + r) * 64 + nt * 16 + l16] = f2bf(acc[nt][r]);
    }
  }
}

// ===========================================================================
// Fused: agg1 = b1 + sum_e w*h1[src]; h2 = mask.relu(agg1)*2; g = h2 @ W2
// 16 nodes/block x 16 lanes/node (R5 shape — per-node fixed cost amortized);
// edge loop unrolled x8 for memory-level parallelism.
// g stored bf16 padded to 32 ch (one 64B line per node).
// ===========================================================================
__global__ __launch_bounds__(256) void agg1_gemm2(const unsigned* __restrict__ offs_g,
                                                  const unsigned* __restrict__ ends_g,
                                                  const unsigned* __restrict__ sortedc,
                                                  const unsigned short* __restrict__ h1b,
                                                  const float* __restrict__ b1,
                                                  const float* __restrict__ W2,
                                                  unsigned* __restrict__ g32u) {
  __shared__ float h2[16][68];
  __shared__ float w2t[20][68];
  const int t = threadIdx.x;
  const int node0 = blockIdx.x * 16;
  for (int i = t; i < 64 * 20; i += 256) {
    w2t[i % 20][i / 20] = W2[i];
  }
  const int n = t >> 4, cg = t & 15;
  const int node = node0 + n;
  const unsigned s = offs_g[node], e_end = ends_g[node];
  float4 acc = *(const float4*)(b1 + cg * 4);
  unsigned i = s;
  for (; i + 8 <= e_end; i += 8) {
    unsigned e0 = sortedc[i],     e1 = sortedc[i + 1], e2 = sortedc[i + 2], e3 = sortedc[i + 3];
    unsigned e4 = sortedc[i + 4], e5 = sortedc[i + 5], e6 = sortedc[i + 6], e7 = sortedc[i + 7];
    uint2 v0 = *(const uint2*)(h1b + ((size_t)(e0 & 0xFFFFu)) * 64 + cg * 4);
    uint2 v1 = *(const uint2*)(h1b + ((size_t)(e1 & 0xFFFFu)) * 64 + cg * 4);
    uint2 v2 = *(const uint2*)(h1b + ((size_t)(e2 & 0xFFFFu)) * 64 + cg * 4);
    uint2 v3 = *(const uint2*)(h1b + ((size_t)(e3 & 0xFFFFu)) * 64 + cg * 4);
    uint2 v4 = *(const uint2*)(h1b + ((size_t)(e4 & 0xFFFFu)) * 64 + cg * 4);
    uint2 v5 = *(const uint2*)(h1b + ((size_t)(e5 & 0xFFFFu)) * 64 + cg * 4);
    uint2 v6 = *(const uint2*)(h1b + ((size_t)(e6 & 0xFFFFu)) * 64 + cg * 4);
    uint2 v7 = *(const uint2*)(h1b + ((size_t)(e7 & 0xFFFFu)) * 64 + cg * 4);
    float w0 = bfhi(e0), w1 = bfhi(e1), w2 = bfhi(e2), w3 = bfhi(e3);
    float w4 = bfhi(e4), w5 = bfhi(e5), w6 = bfhi(e6), w7 = bfhi(e7);
    acc.x = fmaf(w0, bflo(v0.x), acc.x); acc.y = fmaf(w0, bfhi(v0.x), acc.y);
    acc.z = fmaf(w0, bflo(v0.y), acc.z); acc.w = fmaf(w0, bfhi(v0.y), acc.w);
    acc.x = fmaf(w1, bflo(v1.x), acc.x); acc.y = fmaf(w1, bfhi(v1.x), acc.y);
    acc.z = fmaf(w1, bflo(v1.y), acc.z); acc.w = fmaf(w1, bfhi(v1.y), acc.w);
    acc.x = fmaf(w2, bflo(v2.x), acc.x); acc.y = fmaf(w2, bfhi(v2.x), acc.y);
    acc.z = fmaf(w2, bflo(v2.y), acc.z); acc.w = fmaf(w2, bfhi(v2.y), acc.w);
    acc.x = fmaf(w3, bflo(v3.x), acc.x); acc.y = fmaf(w3, bfhi(v3.x), acc.y);
    acc.z = fmaf(w3, bflo(v3.y), acc.z); acc.w = fmaf(w3, bfhi(v3.y), acc.w);
    acc.x = fmaf(w4, bflo(v4.x), acc.x); acc.y = fmaf(w4, bfhi(v4.x), acc.y);
    acc.z = fmaf(w4, bflo(v4.y), acc.z); acc.w = fmaf(w4, bfhi(v4.y), acc.w);
    acc.x = fmaf(w5, bflo(v5.x), acc.x); acc.y = fmaf(w5, bfhi(v5.x), acc.y);
    acc.z = fmaf(w5, bflo(v5.y), acc.z); acc.w = fmaf(w5, bfhi(v5.y), acc.w);
    acc.x = fmaf(w6, bflo(v6.x), acc.x); acc.y = fmaf(w6, bfhi(v6.x), acc.y);
    acc.z = fmaf(w6, bflo(v6.y), acc.z); acc.w = fmaf(w6, bfhi(v6.y), acc.w);
    acc.x = fmaf(w7, bflo(v7.x), acc.x); acc.y = fmaf(w7, bfhi(v7.x), acc.y);
    acc.z = fmaf(w7, bflo(v7.y), acc.z); acc.w = fmaf(w7, bfhi(v7.y), acc.w);
  }
  for (; i < e_end; ++i) {
    unsigned e0 = sortedc[i];
    uint2 v0 = *(const uint2*)(h1b + ((size_t)(e0 & 0xFFFFu)) * 64 + cg * 4);
    float w0 = bfhi(e0);
    acc.x = fmaf(w0, bflo(v0.x), acc.x); acc.y = fmaf(w0, bfhi(v0.x), acc.y);
    acc.z = fmaf(w0, bflo(v0.y), acc.z); acc.w = fmaf(w0, bfhi(v0.y), acc.w);
  }
  const unsigned gi = (unsigned)node * 64u + (unsigned)cg * 4u;
  float r[4] = {acc.x, acc.y, acc.z, acc.w};
#pragma unroll
  for (int j = 0; j < 4; ++j) {
    float v = fmaxf(r[j], 0.0f);
    h2[n][cg * 4 + j] = keep_mask(gi + j) ? v * 2.0f : 0.0f;
  }
  __syncthreads();
  // gemm2 tail: lane cg computes ch {2cg, 2cg+1}; pads (cg>=10) written as 0
  float d0 = 0.0f, d1 = 0.0f;
  if (cg < 10) {
    const int c0 = cg * 2, c1 = cg * 2 + 1;
#pragma unroll
    for (int k = 0; k < 64; k += 4) {
      float4 hv = *(const float4*)(&h2[n][k]);
      float4 w0 = *(const float4*)(&w2t[c0][k]);
      float4 w1 = *(const float4*)(&w2t[c1][k]);
      d0 = fmaf(hv.x, w0.x, d0); d0 = fmaf(hv.y, w0.y, d0);
      d0 = fmaf(hv.z, w0.z, d0); d0 = fmaf(hv.w, w0.w, d0);
      d1 = fmaf(hv.x, w1.x, d1); d1 = fmaf(hv.y, w1.y, d1);
      d1 = fmaf(hv.z, w1.z, d1); d1 = fmaf(hv.w, w1.w, d1);
    }
  }
  unsigned packed = (cg < 10) ? ((unsigned)f2bf(d0) | ((unsigned)f2bf(d1) << 16)) : 0u;
  g32u[(size_t)node * 16 + cg] = packed;
}

// ===========================================================================
// aggregate2: out[n][c] = b2[c] + sum_e w * g[src][c]
// 16 nodes/block x 16 lanes/node, uint gather (2ch), unroll x8.
// ===========================================================================
__global__ __launch_bounds__(256) void aggregate2(const unsigned* __restrict__ offs_g,
                                                  const unsigned* __restrict__ ends_g,
                                                  const unsigned* __restrict__ sortedc,
                                                  const unsigned* __restrict__ g32u,
                                                  const float* __restrict__ b2,
                                                  float* __restrict__ out) {
  const int t = threadIdx.x;
  const int n = blockIdx.x * 16 + (t >> 4);
  const int cg = t & 15;
  const unsigned s = offs_g[n], e_end = ends_g[n];
  float ax = 0.0f, ay = 0.0f;
  unsigned i = s;
  for (; i + 8 <= e_end; i += 8) {
    unsigned e0 = sortedc[i],     e1 = sortedc[i + 1], e2 = sortedc[i + 2], e3 = sortedc[i + 3];
    unsigned e4 = sortedc[i + 4], e5 = sortedc[i + 5], e6 = sortedc[i + 6], e7 = sortedc[i + 7];
    unsigned v0 = g32u[(size_t)(e0 & 0xFFFFu) * 16 + cg];
    unsigned v1 = g32u[(size_t)(e1 & 0xFFFFu) * 16 + cg];
    unsigned v2 = g32u[(size_t)(e2 & 0xFFFFu) * 16 + cg];
    unsigned v3 = g32u[(size_t)(e3 & 0xFFFFu) * 16 + cg];
    unsigned v4 = g32u[(size_t)(e4 & 0xFFFFu) * 16 + cg];
    unsigned v5 = g32u[(size_t)(e5 & 0xFFFFu) * 16 + cg];
    unsigned v6 = g32u[(size_t)(e6 & 0xFFFFu) * 16 + cg];
    unsigned v7 = g32u[(size_t)(e7 & 0xFFFFu) * 16 + cg];
    float w0 = bfhi(e0), w1 = bfhi(e1), w2 = bfhi(e2), w3 = bfhi(e3);
    float w4 = bfhi(e4), w5 = bfhi(e5), w6 = bfhi(e6), w7 = bfhi(e7);
    ax = fmaf(w0, bflo(v0), ax); ay = fmaf(w0, bfhi(v0), ay);
    ax = fmaf(w1, bflo(v1), ax); ay = fmaf(w1, bfhi(v1), ay);
    ax = fmaf(w2, bflo(v2), ax); ay = fmaf(w2, bfhi(v2), ay);
    ax = fmaf(w3, bflo(v3), ax); ay = fmaf(w3, bfhi(v3), ay);
    ax = fmaf(w4, bflo(v4), ax); ay = fmaf(w4, bfhi(v4), ay);
    ax = fmaf(w5, bflo(v5), ax); ay = fmaf(w5, bfhi(v5), ay);
    ax = fmaf(w6, bflo(v6), ax); ay = fmaf(w6, bfhi(v6), ay);
    ax = fmaf(w7, bflo(v7), ax); ay = fmaf(w7, bfhi(v7), ay);
  }
  for (; i < e_end; ++i) {
    unsigned e0 = sortedc[i];
    unsigned v0 = g32u[(size_t)(e0 & 0xFFFFu) * 16 + cg];
    float w0 = bfhi(e0);
    ax = fmaf(w0, bflo(v0), ax); ay = fmaf(w0, bfhi(v0), ay);
  }
  if (cg < 10) {
    float2 o = make_float2(ax + b2[cg * 2], ay + b2[cg * 2 + 1]);
    *(float2*)(out + (size_t)n * 20 + cg * 2) = o;
  }
}

extern "C" void kernel_launch(void* const* d_in, const int* in_sizes, int n_in,
                              void* d_out, int out_size, void* d_ws, size_t ws_size,
                              hipStream_t stream) {
  const float* x  = (const float*)d_in[0];
  const int*   ei = (const int*)d_in[1];
  const float* ew = (const float*)d_in[2];
  const float* W1 = (const float*)d_in[3];
  const float* b1 = (const float*)d_in[4];
  const float* W2 = (const float*)d_in[5];
  const float* b2 = (const float*)d_in[6];
  float* out = (float*)d_out;

  // workspace layout (~27 MB; ws confirmed >= 42 MB)
  unsigned short* h1b     = (unsigned short*)d_ws;                  // N*64 bf16, 8MB
  unsigned*       g32u    = (unsigned*)(h1b + (size_t)N_NODES * 64);// N*16 uint, 4MB
  uint2*          binned  = (uint2*)(g32u + (size_t)N_NODES * 16);  // NB*CAP uint2, 9.4MB
  unsigned*       sortedc = (unsigned*)(binned + (size_t)NB * CAP); // NB*CAP uint, 4.7MB
  unsigned*       offs_g  = sortedc + (size_t)NB * CAP;             // N
  unsigned*       ends_g  = offs_g + N_NODES;                       // N
  unsigned short* Wt      = (unsigned short*)(ends_g + N_NODES);    // 64*320 bf16
  unsigned*       gcur    = (unsigned*)(Wt + 64 * 320);             // NB

  prep_w1<<<(64 * 320 + 255) / 256, 256, 0, stream>>>(W1, Wt, gcur);
  bin_pass<<<BLK_A, 256, 0, stream>>>(ei, ew, gcur, binned);
  bucket_sort<<<NB, 256, 0, stream>>>(gcur, binned, sortedc, offs_g, ends_g);
  gemm1_mfma<<<N_NODES / 64, 256, 0, stream>>>(x, Wt, h1b);
  agg1_gemm2<<<N_NODES / 16, 256, 0, stream>>>(offs_g, ends_g, sortedc, h1b, b1, W2, g32u);
  aggregate2<<<N_NODES / 16, 256, 0, stream>>>(offs_g, ends_g, sortedc, g32u, b2, out);
}

// Round 8
// 222.970 us; speedup vs baseline: 1.2404x; 1.0160x over previous
//
#include <hip/hip_runtime.h>

#define N_NODES 65536
#define N_EDGES 1048576
#define NB 256            // coarse buckets = dst >> 8
#define CAP 4608          // per-bucket capacity: mean 4096 + 8 sigma (binomial)
#define EPB_A 4096        // edges per block in bin_pass
#define BLK_A (N_EDGES / EPB_A)   // 256
#define EPT_A (EPB_A / 256)       // 16 edges per thread

typedef __attribute__((ext_vector_type(8))) short short8v;   // 8 bf16 (4 VGPRs)
typedef __attribute__((ext_vector_type(4))) float float4v;   // MFMA C/D

// fp32 -> bf16 round-to-nearest-even
__device__ __forceinline__ unsigned short f2bf(float f) {
  unsigned u = __float_as_uint(f);
  unsigned r = u + 0x7FFFu + ((u >> 16) & 1u);
  return (unsigned short)(r >> 16);
}
__device__ __forceinline__ float bflo(unsigned u) { return __uint_as_float(u << 16); }
__device__ __forceinline__ float bfhi(unsigned u) { return __uint_as_float(u & 0xFFFF0000u); }

// ---------------------------------------------------------------------------
// JAX threefry2x32, partitionable path: bits[i] = x0^x1 of
// threefry2x32(key=(0,42), counter=(0,i)); keep = MSB==0.  [verified R1]
// ---------------------------------------------------------------------------
__device__ __forceinline__ bool keep_mask(unsigned idx) {
  const unsigned k0 = 0u, k1 = 42u;
  const unsigned k2 = 0x1BD11BDAu ^ k0 ^ k1;
  unsigned x0 = 0u;
  unsigned x1 = idx;
  x0 += k0; x1 += k1;
#define TF_ROUND(r) { x0 += x1; x1 = (x1 << (r)) | (x1 >> (32 - (r))); x1 ^= x0; }
  TF_ROUND(13) TF_ROUND(15) TF_ROUND(26) TF_ROUND(6)
  x0 += k1; x1 += k2 + 1u;
  TF_ROUND(17) TF_ROUND(29) TF_ROUND(16) TF_ROUND(24)
  x0 += k2; x1 += k0 + 2u;
  TF_ROUND(13) TF_ROUND(15) TF_ROUND(26) TF_ROUND(6)
  x0 += k0; x1 += k1 + 3u;
  TF_ROUND(17) TF_ROUND(29) TF_ROUND(16) TF_ROUND(24)
  x0 += k1; x1 += k2 + 4u;
  TF_ROUND(13) TF_ROUND(15) TF_ROUND(26) TF_ROUND(6)
  x0 += k2; x1 += k0 + 5u;
#undef TF_ROUND
  return ((x0 ^ x1) & 0x80000000u) == 0u;
}

// ===========================================================================
// prep_w1: Wt[ch][k] = bf16(W1[k][ch]), K zero-padded 300 -> 320.
// Block 0 also zeroes the 256 bucket cursors (stream order covers bin_pass).
// ===========================================================================
__global__ __launch_bounds__(256) void prep_w1(const float* __restrict__ W1,
                                               unsigned short* __restrict__ Wt,
                                               unsigned* __restrict__ gcur) {
  if (blockIdx.x == 0) gcur[threadIdx.x] = 0u;
  int i = blockIdx.x * 256 + threadIdx.x;
  if (i >= 64 * 320) return;
  int ch = i / 320, k = i % 320;
  float v = (k < 300) ? W1[k * 64 + ch] : 0.0f;
  Wt[i] = f2bf(v);
}

// ===========================================================================
// Sort stage 1: multisplit into fixed-capacity bucket regions.
// pack: x = src | (dst << 16), y = weight fp32 bits
// EPB 4096: per-block fixed cost (scan, cursor grab) amortized over 2x edges.
// ===========================================================================
__global__ __launch_bounds__(256) void bin_pass(const int* __restrict__ ei,
                                                const float* __restrict__ ew,
                                                unsigned* __restrict__ gcur,
                                                uint2* __restrict__ binned) {
  __shared__ unsigned cnt[NB], lofs[NB], lcur[NB], gbase[NB];
  __shared__ uint2 stage[EPB_A];
  const int t = threadIdx.x;
  const int e0 = blockIdx.x * EPB_A;
  cnt[t] = 0u;
  lcur[t] = 0u;
  __syncthreads();
  unsigned pk[EPT_A], pw[EPT_A];
#pragma unroll
  for (int j = 0; j < EPT_A; ++j) {
    int e = e0 + t + j * 256;
    unsigned s = (unsigned)ei[e];
    unsigned d = (unsigned)ei[N_EDGES + e];
    pk[j] = s | (d << 16);
    pw[j] = __float_as_uint(ew[e]);
    atomicAdd(&cnt[d >> 8], 1u);
  }
  __syncthreads();
  lofs[t] = cnt[t];
  __syncthreads();
  for (int d = 1; d < NB; d <<= 1) {
    unsigned u = (t >= d) ? lofs[t - d] : 0u;
    __syncthreads();
    lofs[t] += u;
    __syncthreads();
  }
  unsigned incl = lofs[t];
  lofs[t] = incl - cnt[t];
  gbase[t] = (unsigned)t * CAP + atomicAdd(&gcur[t], cnt[t]);
  __syncthreads();
#pragma unroll
  for (int j = 0; j < EPT_A; ++j) {
    unsigned b = pk[j] >> 24;
    unsigned slot = lofs[b] + atomicAdd(&lcur[b], 1u);
    stage[slot] = make_uint2(pk[j], pw[j]);
  }
  __syncthreads();
  for (int s = t; s < EPB_A; s += 256) {
    uint2 u = stage[s];
    unsigned b = u.x >> 24;
    binned[gbase[b] + ((unsigned)s - lofs[b])] = u;
  }
}

// ===========================================================================
// Sort stage 2: per-bucket counting sort by dst low-8.
// Bucket edges staged to LDS ONCE (single global read); histogram, scan,
// scatter all at LDS speed. Emits packed CSR: offs_p[n] = start | (cnt<<21).
// sorted entry compressed to 4B: src | bf16(w) << 16
// ===========================================================================
__global__ __launch_bounds__(256) void bucket_sort(const unsigned* __restrict__ gcur,
                                                   const uint2* __restrict__ binned,
                                                   unsigned* __restrict__ sortedc,
                                                   unsigned* __restrict__ offs_p) {
  __shared__ uint2 eLDS[CAP];          // 36 KB
  __shared__ unsigned cnt[NB], cur[NB];
  const int t = threadIdx.x;
  const int b = blockIdx.x;
  const unsigned lo = (unsigned)b * CAP;
  const unsigned n_edges = gcur[b];
  cnt[t] = 0u;
  __syncthreads();
  // stage + histogram in one pass
  for (unsigned i = t; i < n_edges; i += 256) {
    uint2 u = binned[lo + i];
    eLDS[i] = u;
    atomicAdd(&cnt[(u.x >> 16) & 255u], 1u);
  }
  __syncthreads();
  cur[t] = cnt[t];
  __syncthreads();
  for (int d = 1; d < NB; d <<= 1) {
    unsigned u = (t >= d) ? cur[t - d] : 0u;
    __syncthreads();
    cur[t] += u;
    __syncthreads();
  }
  unsigned excl = cur[t] - cnt[t];
  // packed CSR: start (21b, < NB*CAP=1179648 < 2^21... actually 2^21=2097152) | count (11b)
  offs_p[b * NB + t] = (lo + excl) | (cnt[t] << 21);
  __syncthreads();
  cur[t] = excl;
  __syncthreads();
  for (unsigned i = t; i < n_edges; i += 256) {
    uint2 u = eLDS[i];
    unsigned lo8 = (u.x >> 16) & 255u;
    unsigned p = lo + atomicAdd(&cur[lo8], 1u);
    sortedc[p] = (u.x & 0xFFFFu) | ((unsigned)f2bf(__uint_as_float(u.y)) << 16);
  }
}

// ===========================================================================
// gemm1_mfma: h1 = x @ W1 via bf16 MFMA 16x16x32; h1 stored bf16 (8 MB).
// ===========================================================================
__global__ __launch_bounds__(256) void gemm1_mfma(const float* __restrict__ x,
                                                  const unsigned short* __restrict__ Wt,
                                                  unsigned short* __restrict__ h1b) {
  __shared__ unsigned short As[64][72];
  __shared__ unsigned short Bs[64][72];
  const int t = threadIdx.x;
  const int node0 = blockIdx.x * 64;
  const int wave = t >> 6, lane = t & 63;
  const int quad = lane >> 4, l16 = lane & 15;
  float4v acc[4] = {{0.f,0.f,0.f,0.f},{0.f,0.f,0.f,0.f},{0.f,0.f,0.f,0.f},{0.f,0.f,0.f,0.f}};

  for (int kt = 0; kt < 5; ++kt) {
    const int k0 = kt * 64;
    for (int f = t; f < 1024; f += 256) {
      int node = f >> 4;
      int k = (f & 15) * 4;
      uint2 packed;
      if (k0 + k < 300) {
        float4 v = *(const float4*)(x + (size_t)(node0 + node) * 300 + k0 + k);
        packed.x = (unsigned)f2bf(v.x) | ((unsigned)f2bf(v.y) << 16);
        packed.y = (unsigned)f2bf(v.z) | ((unsigned)f2bf(v.w) << 16);
      } else {
        packed.x = 0u; packed.y = 0u;
      }
      *(uint2*)&As[node][k] = packed;
    }
    for (int f = t; f < 512; f += 256) {
      int ch = f >> 3;
      int kq = f & 7;
      uint4 v = *(const uint4*)(Wt + (size_t)ch * 320 + k0 + kq * 8);
      *(uint4*)&Bs[ch][kq * 8] = v;
    }
    __syncthreads();
    short8v a0 = *(const short8v*)&As[wave * 16 + l16][quad * 8];
    short8v a1 = *(const short8v*)&As[wave * 16 + l16][32 + quad * 8];
#pragma unroll
    for (int nt = 0; nt < 4; ++nt) {
      short8v b0 = *(const short8v*)&Bs[nt * 16 + l16][quad * 8];
      short8v b1 = *(const short8v*)&Bs[nt * 16 + l16][32 + quad * 8];
      acc[nt] = __builtin_amdgcn_mfma_f32_16x16x32_bf16(a0, b0, acc[nt], 0, 0, 0);
      acc[nt] = __builtin_amdgcn_mfma_f32_16x16x32_bf16(a1, b1, acc[nt], 0, 0, 0);
    }
    __syncthreads();
  }
#pragma unroll
  for (int nt = 0; nt < 4; ++nt) {
#pragma unroll
    for (int r = 0; r < 4; ++r) {
      h1b[(size_t)(node0 + wave * 16 + quad * 4 + r) * 64 + nt * 16 + l16] = f2bf(acc[nt][r]);
    }
  }
}

// ===========================================================================
// Fused: agg1 = b1 + sum_e w*h1[src]; h2 = mask.relu(agg1)*2; g = h2 @ W2
// 16 nodes/block x 16 lanes/node; edge loop unrolled x8 for MLP.
// g stored bf16 padded to 32 ch (one 64B line per node).
// ===========================================================================
__global__ __launch_bounds__(256) void agg1_gemm2(const unsigned* __restrict__ offs_p,
                                                  const unsigned* __restrict__ sortedc,
                                                  const unsigned short* __restrict__ h1b,
                                                  const float* __restrict__ b1,
                                                  const float* __restrict__ W2,
                                                  unsigned* __restrict__ g32u) {
  __shared__ float h2[16][68];
  __shared__ float w2t[20][68];
  const int t = threadIdx.x;
  const int node0 = blockIdx.x * 16;
  for (int i = t; i < 64 * 20; i += 256) {
    w2t[i % 20][i / 20] = W2[i];
  }
  const int n = t >> 4, cg = t & 15;
  const int node = node0 + n;
  const unsigned op = offs_p[node];
  const unsigned s = op & 0x1FFFFFu;
  const unsigned e_end = s + (op >> 21);
  float4 acc = *(const float4*)(b1 + cg * 4);
  unsigned i = s;
  for (; i + 8 <= e_end; i += 8) {
    unsigned e0 = sortedc[i],     e1 = sortedc[i + 1], e2 = sortedc[i + 2], e3 = sortedc[i + 3];
    unsigned e4 = sortedc[i + 4], e5 = sortedc[i + 5], e6 = sortedc[i + 6], e7 = sortedc[i + 7];
    uint2 v0 = *(const uint2*)(h1b + ((size_t)(e0 & 0xFFFFu)) * 64 + cg * 4);
    uint2 v1 = *(const uint2*)(h1b + ((size_t)(e1 & 0xFFFFu)) * 64 + cg * 4);
    uint2 v2 = *(const uint2*)(h1b + ((size_t)(e2 & 0xFFFFu)) * 64 + cg * 4);
    uint2 v3 = *(const uint2*)(h1b + ((size_t)(e3 & 0xFFFFu)) * 64 + cg * 4);
    uint2 v4 = *(const uint2*)(h1b + ((size_t)(e4 & 0xFFFFu)) * 64 + cg * 4);
    uint2 v5 = *(const uint2*)(h1b + ((size_t)(e5 & 0xFFFFu)) * 64 + cg * 4);
    uint2 v6 = *(const uint2*)(h1b + ((size_t)(e6 & 0xFFFFu)) * 64 + cg * 4);
    uint2 v7 = *(const uint2*)(h1b + ((size_t)(e7 & 0xFFFFu)) * 64 + cg * 4);
    float w0 = bfhi(e0), w1 = bfhi(e1), w2 = bfhi(e2), w3 = bfhi(e3);
    float w4 = bfhi(e4), w5 = bfhi(e5), w6 = bfhi(e6), w7 = bfhi(e7);
    acc.x = fmaf(w0, bflo(v0.x), acc.x); acc.y = fmaf(w0, bfhi(v0.x), acc.y);
    acc.z = fmaf(w0, bflo(v0.y), acc.z); acc.w = fmaf(w0, bfhi(v0.y), acc.w);
    acc.x = fmaf(w1, bflo(v1.x), acc.x); acc.y = fmaf(w1, bfhi(v1.x), acc.y);
    acc.z = fmaf(w1, bflo(v1.y), acc.z); acc.w = fmaf(w1, bfhi(v1.y), acc.w);
    acc.x = fmaf(w2, bflo(v2.x), acc.x); acc.y = fmaf(w2, bfhi(v2.x), acc.y);
    acc.z = fmaf(w2, bflo(v2.y), acc.z); acc.w = fmaf(w2, bfhi(v2.y), acc.w);
    acc.x = fmaf(w3, bflo(v3.x), acc.x); acc.y = fmaf(w3, bfhi(v3.x), acc.y);
    acc.z = fmaf(w3, bflo(v3.y), acc.z); acc.w = fmaf(w3, bfhi(v3.y), acc.w);
    acc.x = fmaf(w4, bflo(v4.x), acc.x); acc.y = fmaf(w4, bfhi(v4.x), acc.y);
    acc.z = fmaf(w4, bflo(v4.y), acc.z); acc.w = fmaf(w4, bfhi(v4.y), acc.w);
    acc.x = fmaf(w5, bflo(v5.x), acc.x); acc.y = fmaf(w5, bfhi(v5.x), acc.y);
    acc.z = fmaf(w5, bflo(v5.y), acc.z); acc.w = fmaf(w5, bfhi(v5.y), acc.w);
    acc.x = fmaf(w6, bflo(v6.x), acc.x); acc.y = fmaf(w6, bfhi(v6.x), acc.y);
    acc.z = fmaf(w6, bflo(v6.y), acc.z); acc.w = fmaf(w6, bfhi(v6.y), acc.w);
    acc.x = fmaf(w7, bflo(v7.x), acc.x); acc.y = fmaf(w7, bfhi(v7.x), acc.y);
    acc.z = fmaf(w7, bflo(v7.y), acc.z); acc.w = fmaf(w7, bfhi(v7.y), acc.w);
  }
  for (; i < e_end; ++i) {
    unsigned e0 = sortedc[i];
    uint2 v0 = *(const uint2*)(h1b + ((size_t)(e0 & 0xFFFFu)) * 64 + cg * 4);
    float w0 = bfhi(e0);
    acc.x = fmaf(w0, bflo(v0.x), acc.x); acc.y = fmaf(w0, bfhi(v0.x), acc.y);
    acc.z = fmaf(w0, bflo(v0.y), acc.z); acc.w = fmaf(w0, bfhi(v0.y), acc.w);
  }
  const unsigned gi = (unsigned)node * 64u + (unsigned)cg * 4u;
  float r[4] = {acc.x, acc.y, acc.z, acc.w};
#pragma unroll
  for (int j = 0; j < 4; ++j) {
    float v = fmaxf(r[j], 0.0f);
    h2[n][cg * 4 + j] = keep_mask(gi + j) ? v * 2.0f : 0.0f;
  }
  __syncthreads();
  // gemm2 tail: lane cg computes ch {2cg, 2cg+1}; pads (cg>=10) written as 0
  float d0 = 0.0f, d1 = 0.0f;
  if (cg < 10) {
    const int c0 = cg * 2, c1 = cg * 2 + 1;
#pragma unroll
    for (int k = 0; k < 64; k += 4) {
      float4 hv = *(const float4*)(&h2[n][k]);
      float4 w0 = *(const float4*)(&w2t[c0][k]);
      float4 w1 = *(const float4*)(&w2t[c1][k]);
      d0 = fmaf(hv.x, w0.x, d0); d0 = fmaf(hv.y, w0.y, d0);
      d0 = fmaf(hv.z, w0.z, d0); d0 = fmaf(hv.w, w0.w, d0);
      d1 = fmaf(hv.x, w1.x, d1); d1 = fmaf(hv.y, w1.y, d1);
      d1 = fmaf(hv.z, w1.z, d1); d1 = fmaf(hv.w, w1.w, d1);
    }
  }
  unsigned packed = (cg < 10) ? ((unsigned)f2bf(d0) | ((unsigned)f2bf(d1) << 16)) : 0u;
  g32u[(size_t)node * 16 + cg] = packed;
}

// ===========================================================================
// aggregate2: out[n][c] = b2[c] + sum_e w * g[src][c]
// 16 nodes/block x 16 lanes/node, uint gather (2ch), unroll x8.
// ===========================================================================
__global__ __launch_bounds__(256) void aggregate2(const unsigned* __restrict__ offs_p,
                                                  const unsigned* __restrict__ sortedc,
                                                  const unsigned* __restrict__ g32u,
                                                  const float* __restrict__ b2,
                                                  float* __restrict__ out) {
  const int t = threadIdx.x;
  const int n = blockIdx.x * 16 + (t >> 4);
  const int cg = t & 15;
  const unsigned op = offs_p[n];
  const unsigned s = op & 0x1FFFFFu;
  const unsigned e_end = s + (op >> 21);
  float ax = 0.0f, ay = 0.0f;
  unsigned i = s;
  for (; i + 8 <= e_end; i += 8) {
    unsigned e0 = sortedc[i],     e1 = sortedc[i + 1], e2 = sortedc[i + 2], e3 = sortedc[i + 3];
    unsigned e4 = sortedc[i + 4], e5 = sortedc[i + 5], e6 = sortedc[i + 6], e7 = sortedc[i + 7];
    unsigned v0 = g32u[(size_t)(e0 & 0xFFFFu) * 16 + cg];
    unsigned v1 = g32u[(size_t)(e1 & 0xFFFFu) * 16 + cg];
    unsigned v2 = g32u[(size_t)(e2 & 0xFFFFu) * 16 + cg];
    unsigned v3 = g32u[(size_t)(e3 & 0xFFFFu) * 16 + cg];
    unsigned v4 = g32u[(size_t)(e4 & 0xFFFFu) * 16 + cg];
    unsigned v5 = g32u[(size_t)(e5 & 0xFFFFu) * 16 + cg];
    unsigned v6 = g32u[(size_t)(e6 & 0xFFFFu) * 16 + cg];
    unsigned v7 = g32u[(size_t)(e7 & 0xFFFFu) * 16 + cg];
    float w0 = bfhi(e0), w1 = bfhi(e1), w2 = bfhi(e2), w3 = bfhi(e3);
    float w4 = bfhi(e4), w5 = bfhi(e5), w6 = bfhi(e6), w7 = bfhi(e7);
    ax = fmaf(w0, bflo(v0), ax); ay = fmaf(w0, bfhi(v0), ay);
    ax = fmaf(w1, bflo(v1), ax); ay = fmaf(w1, bfhi(v1), ay);
    ax = fmaf(w2, bflo(v2), ax); ay = fmaf(w2, bfhi(v2), ay);
    ax = fmaf(w3, bflo(v3), ax); ay = fmaf(w3, bfhi(v3), ay);
    ax = fmaf(w4, bflo(v4), ax); ay = fmaf(w4, bfhi(v4), ay);
    ax = fmaf(w5, bflo(v5), ax); ay = fmaf(w5, bfhi(v5), ay);
    ax = fmaf(w6, bflo(v6), ax); ay = fmaf(w6, bfhi(v6), ay);
    ax = fmaf(w7, bflo(v7), ax); ay = fmaf(w7, bfhi(v7), ay);
  }
  for (; i < e_end; ++i) {
    unsigned e0 = sortedc[i];
    unsigned v0 = g32u[(size_t)(e0 & 0xFFFFu) * 16 + cg];
    float w0 = bfhi(e0);
    ax = fmaf(w0, bflo(v0), ax); ay = fmaf(w0, bfhi(v0), ay);
  }
  if (cg < 10) {
    float2 o = make_float2(ax + b2[cg * 2], ay + b2[cg * 2 + 1]);
    *(float2*)(out + (size_t)n * 20 + cg * 2) = o;
  }
}

extern "C" void kernel_launch(void* const* d_in, const int* in_sizes, int n_in,
                              void* d_out, int out_size, void* d_ws, size_t ws_size,
                              hipStream_t stream) {
  const float* x  = (const float*)d_in[0];
  const int*   ei = (const int*)d_in[1];
  const float* ew = (const float*)d_in[2];
  const float* W1 = (const float*)d_in[3];
  const float* b1 = (const float*)d_in[4];
  const float* W2 = (const float*)d_in[5];
  const float* b2 = (const float*)d_in[6];
  float* out = (float*)d_out;

  // workspace layout (~26.5 MB; ws confirmed >= 42 MB)
  unsigned short* h1b     = (unsigned short*)d_ws;                  // N*64 bf16, 8MB
  unsigned*       g32u    = (unsigned*)(h1b + (size_t)N_NODES * 64);// N*16 uint, 4MB
  uint2*          binned  = (uint2*)(g32u + (size_t)N_NODES * 16);  // NB*CAP uint2, 9.4MB
  unsigned*       sortedc = (unsigned*)(binned + (size_t)NB * CAP); // NB*CAP uint, 4.7MB
  unsigned*       offs_p  = sortedc + (size_t)NB * CAP;             // N packed CSR
  unsigned short* Wt      = (unsigned short*)(offs_p + N_NODES);    // 64*320 bf16
  unsigned*       gcur    = (unsigned*)(Wt + 64 * 320);             // NB

  prep_w1<<<(64 * 320 + 255) / 256, 256, 0, stream>>>(W1, Wt, gcur);
  bin_pass<<<BLK_A, 256, 0, stream>>>(ei, ew, gcur, binned);
  bucket_sort<<<NB, 256, 0, stream>>>(gcur, binned, sortedc, offs_p);
  gemm1_mfma<<<N_NODES / 64, 256, 0, stream>>>(x, Wt, h1b);
  agg1_gemm2<<<N_NODES / 16, 256, 0, stream>>>(offs_p, sortedc, h1b, b1, W2, g32u);
  aggregate2<<<N_NODES / 16, 256, 0, stream>>>(offs_p, sortedc, g32u, b2, out);
}